// Round 15
// baseline (108.967 us; speedup 1.0000x reference)
//
#include <hip/hip_runtime.h>

typedef short s16;
typedef unsigned short us16;
typedef signed char i8;
typedef __attribute__((ext_vector_type(8))) short s16x8;
typedef __attribute__((ext_vector_type(8))) unsigned short u16x8;
typedef __attribute__((ext_vector_type(8))) signed char i8x8;
typedef __attribute__((ext_vector_type(16))) signed char i8x16;
typedef __attribute__((ext_vector_type(4))) int i32x4;

#define TOKENS 2048
#define INF    4096
#define OUTF   4096
#define GK     4096

__device__ __forceinline__ us16 f2bf(float f) {
    union { float f; unsigned u; } v; v.f = f;
    unsigned r = v.u + 0x7FFFu + ((v.u >> 16) & 1u);
    return (us16)(r >> 16);
}
__device__ __forceinline__ float bf2f(us16 u) {
    unsigned x = ((unsigned)u) << 16;
    float f; __builtin_memcpy(&f, &x, 4);
    return f;
}

__device__ __forceinline__ void fwht16(float v[16]) {
#pragma unroll
    for (int s = 1; s < 16; s <<= 1)
#pragma unroll
        for (int j = 0; j < 16; ++j)
            if (!(j & s)) {
                float a = v[j], b = v[j + s];
                v[j]     = a + b;
                v[j + s] = a - b;
            }
}

// ---------------------------------------------------------------------------
// Kernel 1: blocks [0,2048): y_i8 = quant(FWHT(x*SU)), per-row scale -> ZS
//           blocks [2048,3072): decompress E8P -> W_i8 = W*4 (EXACT in i8),
//           8 chunks of 256 codes per block (LUT built ONCE per block).
// ---------------------------------------------------------------------------
__global__ __launch_bounds__(256) void k_pre(const float* __restrict__ X,
                                             const float* __restrict__ SU,
                                             i8* __restrict__ Y,
                                             float* __restrict__ ZS,
                                             const int* __restrict__ Q,
                                             const void* __restrict__ gridraw,
                                             i8* __restrict__ W) {
    __shared__ float s[4096 + 272];
    const int tid = threadIdx.x;

    if (blockIdx.x < TOKENS) {
        const int row = blockIdx.x;
        const int hi = tid >> 4, lo = tid & 15;
        float v[16];
        const float* xr = X + (size_t)row * INF;

#pragma unroll
        for (int j = 0; j < 16; ++j) v[j] = xr[j * 256 + tid] * SU[j * 256 + tid];
        fwht16(v);
#pragma unroll
        for (int j = 0; j < 16; ++j) s[272 * j + 17 * hi + lo] = v[j];
        __syncthreads();

#pragma unroll
        for (int j = 0; j < 16; ++j) v[j] = s[272 * hi + 17 * j + lo];
        fwht16(v);
#pragma unroll
        for (int j = 0; j < 16; ++j) s[272 * hi + 17 * j + lo] = v[j];
        __syncthreads();

        const int base = 272 * hi + 17 * lo;
#pragma unroll
        for (int j = 0; j < 16; ++j) v[j] = s[base + j];
        fwht16(v);

        float m16 = 0.f;
#pragma unroll
        for (int j = 0; j < 16; ++j) m16 = fmaxf(m16, fabsf(v[j]));
        __syncthreads();
        s[tid] = m16;
        __syncthreads();
#pragma unroll
        for (int off = 128; off > 0; off >>= 1) {
            if (tid < off) s[tid] = fmaxf(s[tid], s[tid + off]);
            __syncthreads();
        }
        const float vmax = fmaxf(s[0], 1e-30f);
        const float qs = 127.0f / vmax;

        i8x16 o;
#pragma unroll
        for (int j = 0; j < 16; ++j) o[j] = (i8)__float2int_rn(v[j] * qs);
        *reinterpret_cast<i8x16*>(Y + (size_t)row * INF + tid * 16) = o;
        if (tid == 0) ZS[row] = vmax * (0.015625f / 508.0f);  // /64 /(127*4)
    } else {
        float (*gT)[256] = (float(*)[256])s;
        int* gOdd = (int*)(s + 2048);

        const unsigned short* gu = (const unsigned short*)gridraw;
        const float*          gf = (const float*)gridraw;
        const unsigned short  p0 = gu[0];

        float sum = 0.f;
#pragma unroll
        for (int j = 0; j < 8; ++j) {
            float v;
            if (p0 == 0x3800) {                       // float16
                unsigned short u = gu[tid * 8 + j];
                _Float16 hv; __builtin_memcpy(&hv, &u, 2);
                v = (float)hv;
            } else if (p0 == 0x3F00) {                // bfloat16
                v = bf2f(gu[tid * 8 + j]);
            } else {                                  // float32
                v = gf[tid * 8 + j];
            }
            gT[j][tid] = v;
            sum += v;
        }
        gOdd[tid] = ((int)(sum + 0.5f)) & 1;
        __syncthreads();

        const int chunk0 = (blockIdx.x - TOKENS) * 8;
#pragma unroll
        for (int c = 0; c < 8; ++c) {
            const int code = (chunk0 + c) * 256 + tid;
            const int q        = Q[code];
            const int absIdx   = (q >> 8) & 255;
            const int signBits = (q >> 1) & 127;
            const float shift  = (q & 1) ? 1.0f : -1.0f;    // 0.25 * 4
            const int neg0 = (__popc(signBits) ^ gOdd[absIdx]) & 1;

            i8x8 o;
            o[0] = (i8)__float2int_rn(gT[0][absIdx] * 4.0f * (1.0f - 2.0f * (float)neg0) + shift);
#pragma unroll
            for (int i = 1; i < 8; ++i) {
                float sg = 1.0f - 2.0f * (float)((signBits >> (i - 1)) & 1);
                o[i] = (i8)__float2int_rn(gT[i][absIdx] * 4.0f * sg + shift);
            }
            *reinterpret_cast<i8x8*>(W + (size_t)code * 8) = o;
        }
    }
}

// ---------------------------------------------------------------------------
// Kernel 2: GEMM  z[t][j] = sum_k yq[t][k] * wq[j][k]  (NT, K-major, int8)
// 128x256 tile, BK=64 i8, 8 waves (2Mx4N), wave tile 64x64, KSPLIT=2.
// A path: DIRECT global->VGPR (16 rows x 64 contiguous B per fragment read,
// L2-coalesced; panel L2-resident) with next-tile register prefetch. Bytes
// delivered to MFMA are bit-identical to the LDS path (chunk<->lane map
// unchanged). B path: gload_lds(16B) + XOR swizzle, as r14.
// vmcnt ledger/iter: issue [4 A-reg loads(t+1)] + [2 B-DMA(t+2, clamped)];
// boundary vmcnt(2) retires B(t+1)+A(t+1), leaves B(t+2) in flight.
// ---------------------------------------------------------------------------
#define BM 128
#define BN 256
#define BK 64   // i8: 64 B per row-K-slice = 4 x 16B chunks

__global__ __launch_bounds__(512, 4) void k_gemm(const i8* __restrict__ A,
                                                 const i8* __restrict__ B,
                                                 const float* __restrict__ ZS,
                                                 us16* __restrict__ Z0,
                                                 us16* __restrict__ Z1) {
    __shared__ __align__(16) i8 lB[2][BN * BK];   // 2 x 16 KiB (B only)
    const int tid  = threadIdx.x;
    const int lane = tid & 63;
    const int w    = tid >> 6;
    const int wr   = w >> 2, wc = w & 3;
    const int laneRow = lane & 15, laneK = lane >> 4;   // laneK 0..3

    // bijective XCD swizzle over nwg = 512
    const int bid = blockIdx.x;
    const int swz = (bid & 7) * 64 + (bid >> 3);
    const int ks  = swz >> 8;           // 0..1
    const int rem = swz & 255;
    const int mT  = rem >> 4;           // 0..15
    const int nT  = rem & 15;           // 0..15
    const int KT  = (GK / 2) / BK;      // 32
    const size_t kbase = (size_t)ks * (GK / 2);

    us16* __restrict__ Z = (ks == 1) ? Z1 : Z0;

    // ---- A: direct per-lane global pointers (row, k-chunk laneK) ----
    const i8* ap[4];
#pragma unroll
    for (int mi = 0; mi < 4; ++mi) {
        int r = mT * BM + wr * 64 + mi * 16 + laneRow;
        ap[mi] = A + (size_t)r * GK + kbase + (size_t)laneK * 16;
    }

    // ---- B staging: 1024 chunks (2/thread), 16B each ----
    size_t bOff[2];
    int ldsOffB[2];
#pragma unroll
    for (int j = 0; j < 2; ++j) {
        int ch = j * 512 + tid;
        int rr = ch >> 2, cc = ch & 3;
        int sc = cc ^ ((rr >> 1) & 3);
        bOff[j] = (size_t)(nT * BN + rr) * GK + kbase + sc * 16;
        ldsOffB[j] = (j * 512 + w * 64) * 16;
    }

    // B fragment read bases (bytes): row r -> r*64 + (laneK ^ ((r>>1)&3))*16
    int bB[4], bX[4];
#pragma unroll
    for (int nj = 0; nj < 4; ++nj) {
        int r = wc * 64 + nj * 16 + laneRow;
        bB[nj] = r * 64; bX[nj] = (r >> 1) & 3;
    }

    i32x4 acc[4][4] = {};

#define STAGE_B(t, buf) do { const size_t _ko = (size_t)(t) * BK; \
    _Pragma("unroll") \
    for (int j = 0; j < 2; ++j) \
        __builtin_amdgcn_global_load_lds( \
            (const __attribute__((address_space(1))) void*)(B + bOff[j] + _ko), \
            (__attribute__((address_space(3))) void*)(&lB[buf][0] + ldsOffB[j]), 16, 0, 0); \
    } while (0)

    // prologue: A(0) regs, B(0)->buf0, B(1)->buf1; vmcnt(2) leaves B(1) flying
    i32x4 afc[4], afn[4];
#pragma unroll
    for (int mi = 0; mi < 4; ++mi)
        afc[mi] = *reinterpret_cast<const i32x4*>(ap[mi]);
    STAGE_B(0, 0);
    STAGE_B(1, 1);
    asm volatile("s_waitcnt vmcnt(2)" ::: "memory");
    __builtin_amdgcn_sched_barrier(0);
    __builtin_amdgcn_s_barrier();

    int cur = 0;
    for (int t = 0; t < KT; ++t) {
        const i8* pB = &lB[cur][0];

        // issue A(t+1) register prefetch (clamped; keeps vmcnt ledger uniform)
        const size_t an = (size_t)((t + 1 < KT) ? (t + 1) : (KT - 1)) * BK;
#pragma unroll
        for (int mi = 0; mi < 4; ++mi)
            afn[mi] = *reinterpret_cast<const i32x4*>(ap[mi] + an);

        // B fragments from LDS
        i32x4 bf[4];
#pragma unroll
        for (int nj = 0; nj < 4; ++nj)
            bf[nj] = *reinterpret_cast<const i32x4*>(pB + bB[nj] + (laneK ^ bX[nj]) * 16);

        // own LDS reads done; rendezvous -> all waves done reading lB[cur]
        asm volatile("s_waitcnt lgkmcnt(0)" ::: "memory");
        __builtin_amdgcn_sched_barrier(0);
        __builtin_amdgcn_s_barrier();

        // stage B(t+2) into the just-freed buffer (clamped)
        STAGE_B((size_t)((t + 2 < KT) ? (t + 2) : (KT - 1)), cur);

#pragma unroll
        for (int mi = 0; mi < 4; ++mi)
#pragma unroll
            for (int nj = 0; nj < 4; ++nj)
                acc[mi][nj] = __builtin_amdgcn_mfma_i32_16x16x64_i8(
                    afc[mi], bf[nj], acc[mi][nj], 0, 0, 0);

        // boundary: retire B(t+1) DMA + A(t+1) regs; B(t+2) stays in flight
        if (t + 1 < KT) {
            asm volatile("s_waitcnt vmcnt(2)" ::: "memory");
            __builtin_amdgcn_sched_barrier(0);
            __builtin_amdgcn_s_barrier();
        }
#pragma unroll
        for (int mi = 0; mi < 4; ++mi) afc[mi] = afn[mi];
        cur ^= 1;
    }
#undef STAGE_B

    // C/D layout: col = lane&15, row = (lane>>4)*4 + reg
    const int colB = nT * BN + wc * 64 + laneRow;
    const int rowB = mT * BM + wr * 64 + laneK * 4;
#pragma unroll
    for (int mi = 0; mi < 4; ++mi) {
#pragma unroll
        for (int rg = 0; rg < 4; ++rg) {
            const int row = rowB + mi * 16 + rg;
            const float zs = ZS[row];
#pragma unroll
            for (int nj = 0; nj < 4; ++nj)
                Z[(size_t)row * OUTF + colB + nj * 16]
                    = f2bf((float)acc[mi][nj][rg] * zs);
        }
    }
}

// ---------------------------------------------------------------------------
// Kernel 3: OUT = FWHT(bf16 Z0 + bf16 Z1) * Wscale/64 * SV  (digit-reordered)
// ---------------------------------------------------------------------------
__global__ __launch_bounds__(256) void k_out(const us16* __restrict__ Z0,
                                             const us16* __restrict__ Z1,
                                             float* __restrict__ OUT,
                                             const float* __restrict__ SV,
                                             const float* __restrict__ wscale) {
    __shared__ float s[4096 + 272];
    const int row = blockIdx.x, t = threadIdx.x;
    float v[16];
    const us16* zr0 = Z0 + (size_t)row * OUTF;
    const us16* zr1 = Z1 + (size_t)row * OUTF;

    {
        u16x8 a0 = reinterpret_cast<const u16x8*>(zr0 + t * 16)[0];
        u16x8 a1 = reinterpret_cast<const u16x8*>(zr0 + t * 16)[1];
        u16x8 b0 = reinterpret_cast<const u16x8*>(zr1 + t * 16)[0];
        u16x8 b1 = reinterpret_cast<const u16x8*>(zr1 + t * 16)[1];
#pragma unroll
        for (int j = 0; j < 8; ++j) {
            v[j]     = bf2f(a0[j]) + bf2f(b0[j]);
            v[j + 8] = bf2f(a1[j]) + bf2f(b1[j]);
        }
    }
    fwht16(v);
#pragma unroll
    for (int j = 0; j < 16; ++j) s[17 * t + j] = v[j];
    __syncthreads();

    const int pa = 272 * (t >> 4) + (t & 15);
#pragma unroll
    for (int j = 0; j < 16; ++j) v[j] = s[pa + 17 * j];
    fwht16(v);
#pragma unroll
    for (int j = 0; j < 16; ++j) s[pa + 17 * j] = v[j];
    __syncthreads();

    const int pb = 17 * (t >> 4) + (t & 15);
#pragma unroll
    for (int j = 0; j < 16; ++j) v[j] = s[272 * j + pb];
    fwht16(v);

    const float sc = wscale[0] * 0.015625f;
    float* orow = OUT + (size_t)row * OUTF;
#pragma unroll
    for (int j = 0; j < 16; ++j)
        orow[j * 256 + t] = v[j] * sc * SV[j * 256 + t];
}

// ---------------------------------------------------------------------------
extern "C" void kernel_launch(void* const* d_in, const int* in_sizes, int n_in,
                              void* d_out, int out_size, void* d_ws, size_t ws_size,
                              hipStream_t stream) {
    const float* input  = (const float*)d_in[0];   // (2048, 4096) f32
    const int*   Qidxs  = (const int*)d_in[1];     // (4096, 512) i32
    const float* SU     = (const float*)d_in[2];   // (4096,) f32
    const float* SV     = (const float*)d_in[3];   // (4096,) f32
    const float* Wscale = (const float*)d_in[4];   // (1,) f32
    const void*  grid   = (const void*)d_in[9];    // (256, 8) grid_abs

    i8*    W  = (i8*)d_ws;                                         // 16 MB
    i8*    Y  = (i8*)((char*)d_ws + (size_t)16 * 1024 * 1024);     //  8 MB
    us16*  Z0 = (us16*)((char*)d_ws + (size_t)24 * 1024 * 1024);   // 16 MB
    us16*  Z1 = (us16*)((char*)d_ws + (size_t)40 * 1024 * 1024);   // 16 MB
    float* ZS = (float*)((char*)d_ws + (size_t)56 * 1024 * 1024);  //  8 KB

    hipLaunchKernelGGL(k_pre, dim3(TOKENS + 1024), dim3(256), 0, stream,
                       input, SU, Y, ZS, Qidxs, grid, W);
    hipLaunchKernelGGL(k_gemm, dim3(512), dim3(512), 0, stream,
                       Y, W, ZS, Z0, Z1);
    hipLaunchKernelGGL(k_out, dim3(TOKENS), dim3(256), 0, stream,
                       Z0, Z1, (float*)d_out, SV, Wscale);
}

// Round 16
// 72.002 us; speedup vs baseline: 1.5134x; 1.5134x over previous
//
#include <hip/hip_runtime.h>

typedef short s16;
typedef unsigned short us16;
typedef signed char i8;
typedef __attribute__((ext_vector_type(8))) short s16x8;
typedef __attribute__((ext_vector_type(8))) unsigned short u16x8;
typedef __attribute__((ext_vector_type(8))) signed char i8x8;
typedef __attribute__((ext_vector_type(16))) signed char i8x16;
typedef __attribute__((ext_vector_type(4))) int i32x4;

#define TOKENS 2048
#define INF    4096
#define OUTF   4096
#define GK     4096

__device__ __forceinline__ us16 f2bf(float f) {
    union { float f; unsigned u; } v; v.f = f;
    unsigned r = v.u + 0x7FFFu + ((v.u >> 16) & 1u);
    return (us16)(r >> 16);
}
__device__ __forceinline__ float bf2f(us16 u) {
    unsigned x = ((unsigned)u) << 16;
    float f; __builtin_memcpy(&f, &x, 4);
    return f;
}

__device__ __forceinline__ void fwht16(float v[16]) {
#pragma unroll
    for (int s = 1; s < 16; s <<= 1)
#pragma unroll
        for (int j = 0; j < 16; ++j)
            if (!(j & s)) {
                float a = v[j], b = v[j + s];
                v[j]     = a + b;
                v[j + s] = a - b;
            }
}

// ---------------------------------------------------------------------------
// Kernel 1: blocks [0,2048): y_i8 = quant(FWHT(x*SU)), per-row scale -> ZS
//           blocks [2048,3072): decompress E8P -> W_i8 = W*4 (EXACT in i8),
//           8 chunks of 256 codes per block (LUT built ONCE per block).
// ---------------------------------------------------------------------------
__global__ __launch_bounds__(256) void k_pre(const float* __restrict__ X,
                                             const float* __restrict__ SU,
                                             i8* __restrict__ Y,
                                             float* __restrict__ ZS,
                                             const int* __restrict__ Q,
                                             const void* __restrict__ gridraw,
                                             i8* __restrict__ W) {
    __shared__ float s[4096 + 272];
    const int tid = threadIdx.x;

    if (blockIdx.x < TOKENS) {
        const int row = blockIdx.x;
        const int hi = tid >> 4, lo = tid & 15;
        float v[16];
        const float* xr = X + (size_t)row * INF;

#pragma unroll
        for (int j = 0; j < 16; ++j) v[j] = xr[j * 256 + tid] * SU[j * 256 + tid];
        fwht16(v);
#pragma unroll
        for (int j = 0; j < 16; ++j) s[272 * j + 17 * hi + lo] = v[j];
        __syncthreads();

#pragma unroll
        for (int j = 0; j < 16; ++j) v[j] = s[272 * hi + 17 * j + lo];
        fwht16(v);
#pragma unroll
        for (int j = 0; j < 16; ++j) s[272 * hi + 17 * j + lo] = v[j];
        __syncthreads();

        const int base = 272 * hi + 17 * lo;
#pragma unroll
        for (int j = 0; j < 16; ++j) v[j] = s[base + j];
        fwht16(v);

        float m16 = 0.f;
#pragma unroll
        for (int j = 0; j < 16; ++j) m16 = fmaxf(m16, fabsf(v[j]));
        __syncthreads();
        s[tid] = m16;
        __syncthreads();
#pragma unroll
        for (int off = 128; off > 0; off >>= 1) {
            if (tid < off) s[tid] = fmaxf(s[tid], s[tid + off]);
            __syncthreads();
        }
        const float vmax = fmaxf(s[0], 1e-30f);
        const float qs = 127.0f / vmax;

        i8x16 o;
#pragma unroll
        for (int j = 0; j < 16; ++j) o[j] = (i8)__float2int_rn(v[j] * qs);
        *reinterpret_cast<i8x16*>(Y + (size_t)row * INF + tid * 16) = o;
        if (tid == 0) ZS[row] = vmax * (0.015625f / 508.0f);  // /64 /(127*4)
    } else {
        float (*gT)[256] = (float(*)[256])s;
        int* gOdd = (int*)(s + 2048);

        const unsigned short* gu = (const unsigned short*)gridraw;
        const float*          gf = (const float*)gridraw;
        const unsigned short  p0 = gu[0];

        float sum = 0.f;
#pragma unroll
        for (int j = 0; j < 8; ++j) {
            float v;
            if (p0 == 0x3800) {                       // float16
                unsigned short u = gu[tid * 8 + j];
                _Float16 hv; __builtin_memcpy(&hv, &u, 2);
                v = (float)hv;
            } else if (p0 == 0x3F00) {                // bfloat16
                v = bf2f(gu[tid * 8 + j]);
            } else {                                  // float32
                v = gf[tid * 8 + j];
            }
            gT[j][tid] = v;
            sum += v;
        }
        gOdd[tid] = ((int)(sum + 0.5f)) & 1;
        __syncthreads();

        const int chunk0 = (blockIdx.x - TOKENS) * 8;
#pragma unroll
        for (int c = 0; c < 8; ++c) {
            const int code = (chunk0 + c) * 256 + tid;
            const int q        = Q[code];
            const int absIdx   = (q >> 8) & 255;
            const int signBits = (q >> 1) & 127;
            const float shift  = (q & 1) ? 1.0f : -1.0f;    // 0.25 * 4
            const int neg0 = (__popc(signBits) ^ gOdd[absIdx]) & 1;

            i8x8 o;
            o[0] = (i8)__float2int_rn(gT[0][absIdx] * 4.0f * (1.0f - 2.0f * (float)neg0) + shift);
#pragma unroll
            for (int i = 1; i < 8; ++i) {
                float sg = 1.0f - 2.0f * (float)((signBits >> (i - 1)) & 1);
                o[i] = (i8)__float2int_rn(gT[i][absIdx] * 4.0f * sg + shift);
            }
            *reinterpret_cast<i8x8*>(W + (size_t)code * 8) = o;
        }
    }
}

// ---------------------------------------------------------------------------
// Kernel 2: GEMM  z[t][j] = sum_k yq[t][k] * wq[j][k]  (NT, K-major, int8)
// 256x256 tile, BK=64 i8, 8 waves (2Mx4N), wave tile 128x64, KSPLIT=2.
// mfma_i32_16x16x64_i8. r14 counted-vmcnt loop, scaled: {12 ds_read ->
// lgkmcnt(0) -> s_barrier -> STAGE(t+2,cur)[4 DMA] -> 32 MFMA -> vmcnt(4)
// -> s_barrier}. vmcnt(4) retires tile t+1's 4 loads; t+2's stay in flight.
// 12 b128 reads per 32 MFMA (2.67 MFMA/read, was 2.0) — 23% less LDS-read
// traffic per FLOP; barriers per FLOP halved. Same 16B-chunk XOR swizzle.
// ---------------------------------------------------------------------------
#define BM 256
#define BN 256
#define BK 64   // i8: 64 B per row-K-slice = 4 x 16B chunks

__global__ __launch_bounds__(512, 1) void k_gemm(const i8* __restrict__ A,
                                                 const i8* __restrict__ B,
                                                 const float* __restrict__ ZS,
                                                 us16* __restrict__ Z0,
                                                 us16* __restrict__ Z1) {
    __shared__ __align__(16) i8 lA[2][BM * BK];   // 2 x 16 KiB
    __shared__ __align__(16) i8 lB[2][BN * BK];   // 2 x 16 KiB
    const int tid  = threadIdx.x;
    const int lane = tid & 63;
    const int w    = tid >> 6;
    const int wr   = w >> 2, wc = w & 3;           // 2M x 4N
    const int laneRow = lane & 15, laneK = lane >> 4;   // laneK 0..3

    // bijective XCD swizzle over nwg = 256
    const int bid = blockIdx.x;
    const int swz = (bid & 7) * 32 + (bid >> 3);
    const int ks  = swz >> 7;           // 0..1
    const int rem = swz & 127;
    const int mT  = rem >> 4;           // 0..7
    const int nT  = rem & 15;           // 0..15
    const int KT  = (GK / 2) / BK;      // 32
    const size_t kbase = (size_t)ks * (GK / 2);

    us16* __restrict__ Z = (ks == 1) ? Z1 : Z0;

    // staging: A 1024 chunks (2/thread), B 1024 chunks (2/thread), 16B each
    size_t aOff[2], bOff[2];
    int ldsOffA[2], ldsOffB[2];
#pragma unroll
    for (int j = 0; j < 2; ++j) {
        int ch = j * 512 + tid;
        int rr = ch >> 2, cc = ch & 3;
        int sc = cc ^ ((rr >> 1) & 3);
        aOff[j] = (size_t)(mT * BM + rr) * GK + kbase + sc * 16;
        bOff[j] = (size_t)(nT * BN + rr) * GK + kbase + sc * 16;
        ldsOffA[j] = (j * 512 + w * 64) * 16;
        ldsOffB[j] = (j * 512 + w * 64) * 16;
    }

    // fragment read bases (bytes): row r -> r*64 + (laneK ^ ((r>>1)&3))*16
    int aB[2][4], aX[2][4], bB[4], bX[4];
#pragma unroll
    for (int mh = 0; mh < 2; ++mh)
#pragma unroll
        for (int mi = 0; mi < 4; ++mi) {
            int r = wr * 128 + mh * 64 + mi * 16 + laneRow;
            aB[mh][mi] = r * 64; aX[mh][mi] = (r >> 1) & 3;
        }
#pragma unroll
    for (int nj = 0; nj < 4; ++nj) {
        int r = wc * 64 + nj * 16 + laneRow;
        bB[nj] = r * 64; bX[nj] = (r >> 1) & 3;
    }

    i32x4 acc[2][4][4] = {};   // [mh][mi][nj]

#define STAGE(t, buf) do { const size_t _ko = (size_t)(t) * BK; \
    _Pragma("unroll") \
    for (int j = 0; j < 2; ++j) \
        __builtin_amdgcn_global_load_lds( \
            (const __attribute__((address_space(1))) void*)(A + aOff[j] + _ko), \
            (__attribute__((address_space(3))) void*)(&lA[buf][0] + ldsOffA[j]), 16, 0, 0); \
    _Pragma("unroll") \
    for (int j = 0; j < 2; ++j) \
        __builtin_amdgcn_global_load_lds( \
            (const __attribute__((address_space(1))) void*)(B + bOff[j] + _ko), \
            (__attribute__((address_space(3))) void*)(&lB[buf][0] + ldsOffB[j]), 16, 0, 0); \
    } while (0)

    // prologue: stage tiles 0,1; counted wait -> tile 0 landed, tile 1 flying
    STAGE(0, 0);
    STAGE(1, 1);
    asm volatile("s_waitcnt vmcnt(4)" ::: "memory");
    __builtin_amdgcn_sched_barrier(0);
    __builtin_amdgcn_s_barrier();

    int cur = 0;
    for (int t = 0; t < KT; ++t) {
        const i8* pA = &lA[cur][0];
        const i8* pB = &lB[cur][0];

        // all 12 fragment reads for this K-tile
        i32x4 af[2][4], bf[4];
#pragma unroll
        for (int mh = 0; mh < 2; ++mh)
#pragma unroll
            for (int mi = 0; mi < 4; ++mi)
                af[mh][mi] = *reinterpret_cast<const i32x4*>(
                    pA + aB[mh][mi] + (laneK ^ aX[mh][mi]) * 16);
#pragma unroll
        for (int nj = 0; nj < 4; ++nj)
            bf[nj] = *reinterpret_cast<const i32x4*>(
                pB + bB[nj] + (laneK ^ bX[nj]) * 16);

        // own reads in regs; rendezvous -> ALL waves' reads of buf[cur] done
        asm volatile("s_waitcnt lgkmcnt(0)" ::: "memory");
        __builtin_amdgcn_sched_barrier(0);
        __builtin_amdgcn_s_barrier();

        // stage t+2 into the just-freed buffer (DMA, doesn't touch regs)
        if (t + 2 < KT) { STAGE(t + 2, cur); }

#pragma unroll
        for (int mh = 0; mh < 2; ++mh)
#pragma unroll
            for (int mi = 0; mi < 4; ++mi)
#pragma unroll
                for (int nj = 0; nj < 4; ++nj)
                    acc[mh][mi][nj] = __builtin_amdgcn_mfma_i32_16x16x64_i8(
                        af[mh][mi], bf[nj], acc[mh][mi][nj], 0, 0, 0);

        // boundary: counted — tile t+1's 4 loads retired, t+2's in flight
        if (t + 1 < KT) {
            if (t + 2 < KT) {
                asm volatile("s_waitcnt vmcnt(4)" ::: "memory");
            } else {
                asm volatile("s_waitcnt vmcnt(0)" ::: "memory");
            }
            __builtin_amdgcn_sched_barrier(0);
            __builtin_amdgcn_s_barrier();
        }
        cur ^= 1;
    }
#undef STAGE

    // C/D layout: col = lane&15, row = (lane>>4)*4 + reg
    const int colB = nT * BN + wc * 64 + laneRow;
    const int rowB = mT * BM + wr * 128 + laneK * 4;
#pragma unroll
    for (int mh = 0; mh < 2; ++mh) {
#pragma unroll
        for (int mi = 0; mi < 4; ++mi) {
#pragma unroll
            for (int rg = 0; rg < 4; ++rg) {
                const int row = rowB + mh * 64 + mi * 16 + rg;
                const float zs = ZS[row];
#pragma unroll
                for (int nj = 0; nj < 4; ++nj)
                    Z[(size_t)row * OUTF + colB + nj * 16]
                        = f2bf((float)acc[mh][mi][nj][rg] * zs);
            }
        }
    }
}

// ---------------------------------------------------------------------------
// Kernel 3: OUT = FWHT(bf16 Z0 + bf16 Z1) * Wscale/64 * SV  (digit-reordered)
// ---------------------------------------------------------------------------
__global__ __launch_bounds__(256) void k_out(const us16* __restrict__ Z0,
                                             const us16* __restrict__ Z1,
                                             float* __restrict__ OUT,
                                             const float* __restrict__ SV,
                                             const float* __restrict__ wscale) {
    __shared__ float s[4096 + 272];
    const int row = blockIdx.x, t = threadIdx.x;
    float v[16];
    const us16* zr0 = Z0 + (size_t)row * OUTF;
    const us16* zr1 = Z1 + (size_t)row * OUTF;

    {
        u16x8 a0 = reinterpret_cast<const u16x8*>(zr0 + t * 16)[0];
        u16x8 a1 = reinterpret_cast<const u16x8*>(zr0 + t * 16)[1];
        u16x8 b0 = reinterpret_cast<const u16x8*>(zr1 + t * 16)[0];
        u16x8 b1 = reinterpret_cast<const u16x8*>(zr1 + t * 16)[1];
#pragma unroll
        for (int j = 0; j < 8; ++j) {
            v[j]     = bf2f(a0[j]) + bf2f(b0[j]);
            v[j + 8] = bf2f(a1[j]) + bf2f(b1[j]);
        }
    }
    fwht16(v);
#pragma unroll
    for (int j = 0; j < 16; ++j) s[17 * t + j] = v[j];
    __syncthreads();

    const int pa = 272 * (t >> 4) + (t & 15);
#pragma unroll
    for (int j = 0; j < 16; ++j) v[j] = s[pa + 17 * j];
    fwht16(v);
#pragma unroll
    for (int j = 0; j < 16; ++j) s[pa + 17 * j] = v[j];
    __syncthreads();

    const int pb = 17 * (t >> 4) + (t & 15);
#pragma unroll
    for (int j = 0; j < 16; ++j) v[j] = s[272 * j + pb];
    fwht16(v);

    const float sc = wscale[0] * 0.015625f;
    float* orow = OUT + (size_t)row * OUTF;
#pragma unroll
    for (int j = 0; j < 16; ++j)
        orow[j * 256 + t] = v[j] * sc * SV[j * 256 + t];
}

// ---------------------------------------------------------------------------
extern "C" void kernel_launch(void* const* d_in, const int* in_sizes, int n_in,
                              void* d_out, int out_size, void* d_ws, size_t ws_size,
                              hipStream_t stream) {
    const float* input  = (const float*)d_in[0];   // (2048, 4096) f32
    const int*   Qidxs  = (const int*)d_in[1];     // (4096, 512) i32
    const float* SU     = (const float*)d_in[2];   // (4096,) f32
    const float* SV     = (const float*)d_in[3];   // (4096,) f32
    const float* Wscale = (const float*)d_in[4];   // (1,) f32
    const void*  grid   = (const void*)d_in[9];    // (256, 8) grid_abs

    i8*    W  = (i8*)d_ws;                                         // 16 MB
    i8*    Y  = (i8*)((char*)d_ws + (size_t)16 * 1024 * 1024);     //  8 MB
    us16*  Z0 = (us16*)((char*)d_ws + (size_t)24 * 1024 * 1024);   // 16 MB
    us16*  Z1 = (us16*)((char*)d_ws + (size_t)40 * 1024 * 1024);   // 16 MB
    float* ZS = (float*)((char*)d_ws + (size_t)56 * 1024 * 1024);  //  8 KB

    hipLaunchKernelGGL(k_pre, dim3(TOKENS + 1024), dim3(256), 0, stream,
                       input, SU, Y, ZS, Qidxs, grid, W);
    hipLaunchKernelGGL(k_gemm, dim3(256), dim3(512), 0, stream,
                       Y, W, ZS, Z0, Z1);
    hipLaunchKernelGGL(k_out, dim3(TOKENS), dim3(256), 0, stream,
                       Z0, Z1, (float*)d_out, SV, Wscale);
}